// Round 10
// baseline (289.520 us; speedup 1.0000x reference)
//
#include <hip/hip_runtime.h>

typedef short bf16x8 __attribute__((ext_vector_type(8)));
typedef float f32x4 __attribute__((ext_vector_type(4)));
typedef unsigned int u32x4 __attribute__((ext_vector_type(4)));

// ---------- helpers ----------
__device__ __forceinline__ unsigned short f2bf(float f) {
    unsigned int u = __float_as_uint(f);
    u = (u + 0x7fff + ((u >> 16) & 1)) >> 16;   // RNE
    return (unsigned short)u;
}
__device__ __forceinline__ float bf2f(short s) {
    return __uint_as_float(((unsigned int)(unsigned short)s) << 16);
}

__device__ __forceinline__ void async16(const void* g, void* l) {
    __builtin_amdgcn_global_load_lds(
        (const __attribute__((address_space(1))) void*)g,
        (__attribute__((address_space(3))) void*)l,
        16 /*bytes*/, 0 /*offset*/, 0 /*aux*/);
}

// ---------- fused fp32 -> bf16 cast of all four inputs (one launch) ----------
// regions (float4 units): x 2097152 | wq 1048576 | wkv 524288 | wo 1048576
__global__ __launch_bounds__(256) void castall(const float* __restrict__ x,
                                               const float* __restrict__ wq,
                                               const float* __restrict__ wkv,
                                               const float* __restrict__ wo,
                                               unsigned short* __restrict__ xb,
                                               unsigned short* __restrict__ wqkvb,
                                               unsigned short* __restrict__ wob) {
    int i = blockIdx.x * blockDim.x + threadIdx.x;
    const float* src; unsigned short* dst; int j;
    if (i < 2097152)      { src = x;   dst = xb;    j = i; }
    else if (i < 3145728) { src = wq;  dst = wqkvb; j = i - 2097152; }
    else if (i < 3670016) { src = wkv; dst = wqkvb + (size_t)2048 * 2048; j = i - 3145728; }
    else                  { src = wo;  dst = wob;   j = i - 3670016; }
    float4 f = ((const float4*)src)[j];
    ushort4 u;
    u.x = f2bf(f.x); u.y = f2bf(f.y); u.z = f2bf(f.z); u.w = f2bf(f.w);
    ((ushort4*)dst)[j] = u;
}

// ---------- GEMM 2-phase: C[M,N] = A[M,K] @ B[N,K]^T ----------
// BM=256, BN=NREP*64, BK=64, 512 threads = 8 waves (4 wm x 2 wn).
// Per wave: 64 rows x NREP*32 cols -> acc[4][2*NREP] f32x4.
// TWO barriers per K-tile (was 8): phase0 = {stage NCH-3 of t+1; vmcnt(NCH-3);
// barrier; read all B + A-pair; lgkm0; MFMA}, phase1 = {stage 3; read A-pair;
// lgkm0; MFMA; barrier}. B frags held in regs across both phases. Waves drift
// between barriers -> ds_read and MFMA overlap across waves (the 4-phase
// lockstep serialized them: MfmaUtil 33% == MFMA/(MFMA+LDS) exactly).
// Hazards: tile-t reads covered by phase0 vmcnt+barrier (all waves' DMA
// visible); t+2 overwrite of buf(t) issued only after t's closing barrier,
// by which every wave's reads retired (own lgkm0 before MFMA before barrier).
// If VtOut != nullptr (QKV gemm): cols >= 2560 are V -> written TRANSPOSED.
template <int NREP, typename OutT>
__global__ __launch_bounds__(512, 2) void gemm2p(const unsigned short* __restrict__ A,
                                                 const unsigned short* __restrict__ B,
                                                 OutT* __restrict__ C,
                                                 unsigned short* __restrict__ VtOut,
                                                 int N, int K, int NT,
                                                 int ncut, float qscale) {
    constexpr int NCH = 4 + NREP;   // chunks per K-tile (4 A + NREP B)
    constexpr int S0  = NCH - 3;    // chunks staged in phase 0 (phase 1 stages 3)
    constexpr int NJ  = 2 * NREP;   // col frags per wave
    __shared__ __attribute__((aligned(16))) unsigned short LA[2][256 * 64];
    __shared__ __attribute__((aligned(16))) unsigned short LB[2][NREP * 64 * 64];

    const int tid  = threadIdx.x;
    const int lane = tid & 63;
    const int w    = tid >> 6;          // 0..7
    const int quad = lane >> 4;
    const int l16  = lane & 15;
    const int wm   = w >> 1;            // 0..3 (64-row group)
    const int wn   = w & 1;             // 0..1 (NREP*32-col group)
    const int m0   = blockIdx.x * 256;
    const int n0   = blockIdx.y * (NREP * 64);
    const int swz  = (l16 & 7) << 3;    // read-side XOR swizzle (elements)

    // staging: lane -> (row-in-8, slot); source slot inverse-swizzled
    const int lr = lane >> 3;
    const int ls = lane & 7;
    const int ss = ls ^ lr;
    const unsigned short* aSrc = A + (size_t)(m0 + w * 8 + lr) * K + ss * 8;
    const unsigned short* bSrc = B + (size_t)(n0 + w * 8 + lr) * K + ss * 8;

    f32x4 acc[4][NJ] = {};

    // stage one 8KB chunk (slot si of K-tile t) into buffer nb
    auto stage1 = [&](int nb, int t, int si) {
        if (si < NREP) {
            async16(bSrc + (size_t)si * 64 * K + t * 64, &LB[nb][(si * 64 + w * 8) * 64]);
        } else {
            int c = si - NREP;
            async16(aSrc + (size_t)c * 64 * K + t * 64, &LA[nb][(c * 64 + w * 8) * 64]);
        }
    };

    // prologue: stage all chunks of tile 0 into buffer 0
#pragma unroll
    for (int s = 0; s < NCH; ++s) stage1(0, 0, s);

    for (int t = 0; t < NT; ++t) {
        const int cur  = t & 1;
        const bool more = (t + 1 < NT);

        // ---- phase 0 ----
        if (more) {
#pragma unroll
            for (int s = 0; s < S0; ++s) stage1(cur ^ 1, t + 1, s);
            asm volatile("s_waitcnt vmcnt(%0)" :: "i"(S0) : "memory");
        } else {
            asm volatile("s_waitcnt vmcnt(0)" ::: "memory");
        }
        __builtin_amdgcn_s_barrier();

        bf16x8 bf[NJ][2];
#pragma unroll
        for (int n = 0; n < NJ; ++n)
#pragma unroll
            for (int kk = 0; kk < 2; ++kk)
                bf[n][kk] = *(const bf16x8*)&LB[cur][(size_t)(wn * (NJ * 16) + n * 16 + l16) * 64
                                                     + ((kk * 32 + quad * 8) ^ swz)];
        bf16x8 af[2][2];
#pragma unroll
        for (int mi = 0; mi < 2; ++mi)
#pragma unroll
            for (int kk = 0; kk < 2; ++kk)
                af[mi][kk] = *(const bf16x8*)&LA[cur][(size_t)(wm * 64 + mi * 16 + l16) * 64
                                                      + ((kk * 32 + quad * 8) ^ swz)];
        asm volatile("s_waitcnt lgkmcnt(0)" ::: "memory");
        __builtin_amdgcn_sched_barrier(0);
        __builtin_amdgcn_s_setprio(1);
#pragma unroll
        for (int mi = 0; mi < 2; ++mi)
#pragma unroll
            for (int n = 0; n < NJ; ++n)
#pragma unroll
                for (int kk = 0; kk < 2; ++kk)
                    acc[mi][n] = __builtin_amdgcn_mfma_f32_16x16x32_bf16(
                        af[mi][kk], bf[n][kk], acc[mi][n], 0, 0, 0);
        __builtin_amdgcn_s_setprio(0);

        // ---- phase 1 ----
        if (more) {
#pragma unroll
            for (int s = S0; s < NCH; ++s) stage1(cur ^ 1, t + 1, s);
        }
#pragma unroll
        for (int mi = 0; mi < 2; ++mi)
#pragma unroll
            for (int kk = 0; kk < 2; ++kk)
                af[mi][kk] = *(const bf16x8*)&LA[cur][(size_t)(wm * 64 + 32 + mi * 16 + l16) * 64
                                                      + ((kk * 32 + quad * 8) ^ swz)];
        asm volatile("s_waitcnt lgkmcnt(0)" ::: "memory");
        __builtin_amdgcn_sched_barrier(0);
        __builtin_amdgcn_s_setprio(1);
#pragma unroll
        for (int mi = 0; mi < 2; ++mi)
#pragma unroll
            for (int n = 0; n < NJ; ++n)
#pragma unroll
                for (int kk = 0; kk < 2; ++kk)
                    acc[2 + mi][n] = __builtin_amdgcn_mfma_f32_16x16x32_bf16(
                        af[mi][kk], bf[n][kk], acc[2 + mi][n], 0, 0, 0);
        __builtin_amdgcn_s_setprio(0);
        __builtin_amdgcn_s_barrier();       // closing: protects buf(t) from t+2 stages
    }

    // epilogue
#pragma unroll
    for (int am = 0; am < 4; ++am) {
        int row = m0 + wm * 64 + am * 16 + quad * 4;
#pragma unroll
        for (int n = 0; n < NJ; ++n) {
            int col = n0 + wn * (NJ * 16) + n * 16 + l16;
            f32x4 v = acc[am][n];
            float s = (col < ncut) ? qscale : 1.0f;
            if (VtOut != nullptr && col >= 2560) {
                // V column -> transposed write only: Vt[b*512 + (col-2560)][t0..t0+3]
                int bb = row >> 11, t0 = row & 2047;
                ushort4 o;
                o.x = f2bf(v[0]); o.y = f2bf(v[1]); o.z = f2bf(v[2]); o.w = f2bf(v[3]);
                *(ushort4*)(VtOut + ((size_t)(bb * 512 + (col - 2560))) * 2048 + t0) = o;
            } else {
#pragma unroll
                for (int j = 0; j < 4; ++j) {
                    float vj = v[j] * s;
                    if constexpr (sizeof(OutT) == 4)
                        C[(size_t)(row + j) * N + col] = vj;
                    else
                        C[(size_t)(row + j) * N + col] = f2bf(vj);
                }
            }
        }
    }
}

// ---------- Flash attention v9b: split-K + permlane P-redistribution ----------
__global__ __launch_bounds__(256, 2) void attn_fwd9(const unsigned short* __restrict__ QKV,
                                                    const unsigned short* __restrict__ Vt,
                                                    unsigned short* __restrict__ Opart,
                                                    float* __restrict__ lpart) {
    __shared__ __attribute__((aligned(16))) unsigned short Ks[64 * 128];     // single
    __shared__ __attribute__((aligned(16))) unsigned short Vs[2][128 * 64];  // double

    const int tid  = threadIdx.x;
    const int lane = tid & 63;
    const int w    = tid >> 6;
    const int quad = lane >> 4;
    const int l16  = lane & 15;
    const int swz  = (l16 & 7) << 3;

    const int hb   = blockIdx.x;
    const int h    = hb & 15;
    const int b    = hb >> 4;
    const int y    = blockIdx.y;
    const int p    = 15 - (y >> 1);
    const int half = y & 1;
    const int kvh  = h >> 2;
    const float M_FIX = 12.0f;

    const int ntot   = p + 1;
    const int tstart = half ? ntot : 0;
    const int tend   = half ? 2 * ntot : ntot;

    const int qbase = p * 128;
    const int qw0   = qbase + w * 32;
    const int qw1   = qw0 + 16;

    bf16x8 qf[2][4];
#pragma unroll
    for (int g = 0; g < 2; ++g)
#pragma unroll
        for (int kd = 0; kd < 4; ++kd)
            qf[g][kd] = *(const bf16x8*)(QKV + (size_t)(b * 2048 + qw0 + g * 16 + l16) * 3072
                                         + h * 128 + kd * 32 + quad * 8);

    f32x4 oacc[2][8] = {};
    f32x4 rs4[2] = {};

    const unsigned short* gk[4];
    const unsigned short* gv[4];
#pragma unroll
    for (int pp = 0; pp < 4; ++pp) {
        int r  = (4 * w + pp) * 4 + (lane >> 4);
        int s  = lane & 15;
        int sp = (s & 8) | ((s ^ r) & 7);
        gk[pp] = QKV + (size_t)(b * 2048 + r) * 3072 + 2048 + kvh * 128 + sp * 8;
        int d  = (4 * w + pp) * 8 + (lane >> 3);
        int sv = (lane & 7) ^ (d & 7);
        gv[pp] = Vt + ((size_t)(b * 4 + kvh) * 128 + d) * 2048 + sv * 8;
    }

    auto stageK = [&](int t) {
        const size_t ko = (size_t)t * 64;
#pragma unroll
        for (int pp = 0; pp < 4; ++pp)
            async16(gk[pp] + ko * 3072, &Ks[(4 * w + pp) * 512]);
    };
    auto stageV = [&](int nb, int t) {
        const size_t ko = (size_t)t * 64;
#pragma unroll
        for (int pp = 0; pp < 4; ++pp)
            async16(gv[pp] + ko, &Vs[nb][(4 * w + pp) * 512]);
    };

    stageK(tstart);
    stageV(0, tstart);
    int cur = 0;

    for (int t = tstart; t < tend; ++t) {
        __syncthreads();                          // sync1: K(t)/V(t) DMA drained
        if (t + 1 < tend) stageV(cur ^ 1, t + 1); // early V prefetch (Vs[nxt] free)
        const int k0 = t * 64;
        const bool liveW = (k0 <= qw0 + 15);
        const bool live1 = (k0 <= qw1 + 15);

        bf16x8 pa[2][2];
        if (liveW) {
            // ---- S^T = K Q^T : lane holds q-row = l16, keys kt*16+quad*4+j ----
            f32x4 sacc[2][4] = {};
            __builtin_amdgcn_s_setprio(1);
#pragma unroll
            for (int kt = 0; kt < 4; ++kt) {
                bf16x8 kf[4];
#pragma unroll
                for (int kd = 0; kd < 4; ++kd)
                    kf[kd] = *(const bf16x8*)&Ks[(kt * 16 + l16) * 128
                                                 + ((kd * 32 + quad * 8) ^ swz)];
#pragma unroll
                for (int kd = 0; kd < 4; ++kd)
                    sacc[0][kt] = __builtin_amdgcn_mfma_f32_16x16x32_bf16(kf[kd], qf[0][kd], sacc[0][kt], 0, 0, 0);
                if (live1) {
#pragma unroll
                    for (int kd = 0; kd < 4; ++kd)
                        sacc[1][kt] = __builtin_amdgcn_mfma_f32_16x16x32_bf16(kf[kd], qf[1][kd], sacc[1][kt], 0, 0, 0);
                }
            }
            __builtin_amdgcn_s_setprio(0);

            // ---- in-register softmax + pack + permlane redistribution ----
#pragma unroll
            for (int g = 0; g < 2; ++g) {
                if (g == 1 && !live1) continue;
                const int qwg  = qw0 + g * 16;
                const bool diag = (k0 + 63 > qwg);
                const int qrow = qwg + l16;
                unsigned int pk[4][2];
#pragma unroll
                for (int kt = 0; kt < 4; ++kt) {
                    float pvv[4];
#pragma unroll
                    for (int j = 0; j < 4; ++j) {
                        float pv = __expf(sacc[g][kt][j] - M_FIX);
                        if (diag) {
                            int key = k0 + kt * 16 + quad * 4 + j;
                            if (key > qrow) pv = 0.f;
                        }
                        rs4[g][j] += pv;
                        pvv[j] = pv;
                    }
                    asm("v_cvt_pk_bf16_f32 %0, %1, %2" : "=v"(pk[kt][0]) : "v"(pvv[0]), "v"(pvv[1]));
                    asm("v_cvt_pk_bf16_f32 %0, %1, %2" : "=v"(pk[kt][1]) : "v"(pvv[2]), "v"(pvv[3]));
                }
#pragma unroll
                for (int ks = 0; ks < 2; ++ks) {
                    unsigned int d0 = pk[2 * ks][0], s0 = pk[2 * ks + 1][0];
                    unsigned int d1 = pk[2 * ks][1], s1 = pk[2 * ks + 1][1];
                    asm("v_permlane32_swap_b32 %0, %1" : "+v"(d0), "+v"(s0));
                    asm("v_permlane16_swap_b32 %0, %1" : "+v"(d0), "+v"(s0));
                    asm("v_permlane32_swap_b32 %0, %1" : "+v"(d1), "+v"(s1));
                    asm("v_permlane16_swap_b32 %0, %1" : "+v"(d1), "+v"(s1));
                    u32x4 tt;
                    tt.x = d0;
                    tt.y = d1;
                    tt.z = s0;
                    tt.w = s1;
                    pa[g][ks] = __builtin_bit_cast(bf16x8, tt);
                }
            }
        }

        // sync2: all Ks ds_reads retired (lgkm-only; V prefetch stays in flight)
        asm volatile("s_waitcnt lgkmcnt(0)" ::: "memory");
        __builtin_amdgcn_s_barrier();
        if (t + 1 < tend) stageK(t + 1);          // overwrite single Ks with K(t+1)

        if (liveW) {
            // ---- O += P V ----
            __builtin_amdgcn_s_setprio(1);
#pragma unroll
            for (int dt = 0; dt < 8; ++dt) {
                bf16x8 vf[2];
#pragma unroll
                for (int ks = 0; ks < 2; ++ks)
                    vf[ks] = *(const bf16x8*)&Vs[cur][(dt * 16 + l16) * 64
                                                      + ((ks * 32 + quad * 8) ^ swz)];
#pragma unroll
                for (int ks = 0; ks < 2; ++ks)
                    oacc[0][dt] = __builtin_amdgcn_mfma_f32_16x16x32_bf16(pa[0][ks], vf[ks], oacc[0][dt], 0, 0, 0);
                if (live1) {
#pragma unroll
                    for (int ks = 0; ks < 2; ++ks)
                        oacc[1][dt] = __builtin_amdgcn_mfma_f32_16x16x32_bf16(pa[1][ks], vf[ks], oacc[1][dt], 0, 0, 0);
                }
            }
            __builtin_amdgcn_s_setprio(0);
        }
        cur ^= 1;
    }

    // ---- epilogue: UNNORMALIZED partial O (bf16) and partial l (fp32) ----
#pragma unroll
    for (int g = 0; g < 2; ++g) {
        float r = (rs4[g][0] + rs4[g][1]) + (rs4[g][2] + rs4[g][3]);
        r += __shfl_xor(r, 16, 64);
        r += __shfl_xor(r, 32, 64);
        if (lane < 16)
            lpart[((size_t)(half * 2 + b) * 16 + h) * 2048 + qw0 + g * 16 + lane] = r;
#pragma unroll
        for (int dt = 0; dt < 8; ++dt)
#pragma unroll
            for (int j = 0; j < 4; ++j) {
                int qrow = qw0 + g * 16 + quad * 4 + j;
                Opart[(size_t)(half * 4096 + b * 2048 + qrow) * 2048 + h * 128 + dt * 16 + l16] =
                    f2bf(oacc[g][dt][j]);
            }
    }
}

// ---------- combine: O = (O_A + O_B) / (l_A + l_B) ----------
__global__ __launch_bounds__(256) void combine(const unsigned short* __restrict__ Opart,
                                               const float* __restrict__ lpart,
                                               unsigned short* __restrict__ O) {
    const int r   = blockIdx.x;
    const int b   = r >> 11, row = r & 2047;
    const int col = threadIdx.x * 8;
    const int h   = col >> 7;
    bf16x8 a = *(const bf16x8*)(Opart + (size_t)r * 2048 + col);
    bf16x8 c = *(const bf16x8*)(Opart + (size_t)(4096 + r) * 2048 + col);
    float la = lpart[((size_t)(0 * 2 + b) * 16 + h) * 2048 + row];
    float lb = lpart[((size_t)(1 * 2 + b) * 16 + h) * 2048 + row];
    float inv = 1.0f / (la + lb);
    bf16x8 o;
#pragma unroll
    for (int i = 0; i < 8; ++i)
        o[i] = (short)f2bf((bf2f(a[i]) + bf2f(c[i])) * inv);
    *(bf16x8*)(O + (size_t)r * 2048 + col) = o;
}

// ---------- launch ----------
extern "C" void kernel_launch(void* const* d_in, const int* in_sizes, int n_in,
                              void* d_out, int out_size, void* d_ws, size_t ws_size,
                              hipStream_t stream) {
    const float* x   = (const float*)d_in[0];   // [2,2048,2048]
    const float* wq  = (const float*)d_in[1];   // [2048,2048]
    const float* wkv = (const float*)d_in[2];   // [1024,2048]
    const float* wo  = (const float*)d_in[3];   // [2048,2048]
    float* out = (float*)d_out;                 // [2,2048,2048] fp32

    char* ws = (char*)d_ws;
    size_t off = 0;
    auto alloc = [&](size_t bytes) { size_t o = off; off += (bytes + 255) & ~(size_t)255; return o; };
    unsigned short* xb    = (unsigned short*)(ws + alloc((size_t)4096 * 2048 * 2));
    unsigned short* wqkvb = (unsigned short*)(ws + alloc((size_t)3072 * 2048 * 2));
    unsigned short* wob   = (unsigned short*)(ws + alloc((size_t)2048 * 2048 * 2));
    unsigned short* QKVb  = (unsigned short*)(ws + alloc((size_t)4096 * 3072 * 2));
    unsigned short* Ab    = (unsigned short*)(ws + alloc((size_t)4096 * 2048 * 2));
    unsigned short* Vtb   = (unsigned short*)(ws + alloc((size_t)2 * 4 * 128 * 2048 * 2));
    unsigned short* Opart = (unsigned short*)(ws + alloc((size_t)2 * 4096 * 2048 * 2));
    float*          lpart = (float*)(ws + alloc((size_t)2 * 2 * 16 * 2048 * 4));

    const float qscale = 0.08838834764831845f;  // 1/sqrt(128), folded into Q

    // fused casts (x, wq, wkv, wo) in one launch
    castall<<<18432, 256, 0, stream>>>(x, wq, wkv, wo, xb, wqkvb, wob);

    // fused QKV projection (Q cols pre-scaled; V cols written transposed to Vtb)
    gemm2p<3, unsigned short><<<dim3(16, 16), 512, 0, stream>>>(xb, wqkvb, QKVb, Vtb,
                                                                3072, 2048, 32, 2048, qscale);

    // attention: 128-row q-jobs, split-K halves, heavy-first LPT refill; then combine
    attn_fwd9<<<dim3(32, 32), 256, 0, stream>>>(QKVb, Vtb, Opart, lpart);
    combine<<<4096, 256, 0, stream>>>(Opart, lpart, Ab);

    // output projection (fp32 out): 256x128 tiles -> 256 blocks (full GPU)
    gemm2p<2, float><<<dim3(16, 16), 512, 0, stream>>>(Ab, wob, out, nullptr,
                                                       2048, 2048, 32, 0, 1.0f);
}

// Round 11
// 273.429 us; speedup vs baseline: 1.0589x; 1.0589x over previous
//
#include <hip/hip_runtime.h>

typedef short bf16x8 __attribute__((ext_vector_type(8)));
typedef float f32x4 __attribute__((ext_vector_type(4)));
typedef unsigned int u32x4 __attribute__((ext_vector_type(4)));

// ---------- helpers ----------
__device__ __forceinline__ unsigned short f2bf(float f) {
    unsigned int u = __float_as_uint(f);
    u = (u + 0x7fff + ((u >> 16) & 1)) >> 16;   // RNE
    return (unsigned short)u;
}
__device__ __forceinline__ float bf2f(short s) {
    return __uint_as_float(((unsigned int)(unsigned short)s) << 16);
}

__device__ __forceinline__ void async16(const void* g, void* l) {
    __builtin_amdgcn_global_load_lds(
        (const __attribute__((address_space(1))) void*)g,
        (__attribute__((address_space(3))) void*)l,
        16 /*bytes*/, 0 /*offset*/, 0 /*aux*/);
}

// ---------- fused fp32 -> bf16 cast of all four inputs (one launch) ----------
// regions (float4 units): x 2097152 | wq 1048576 | wkv 524288 | wo 1048576
__global__ __launch_bounds__(256) void castall(const float* __restrict__ x,
                                               const float* __restrict__ wq,
                                               const float* __restrict__ wkv,
                                               const float* __restrict__ wo,
                                               unsigned short* __restrict__ xb,
                                               unsigned short* __restrict__ wqkvb,
                                               unsigned short* __restrict__ wob) {
    int i = blockIdx.x * blockDim.x + threadIdx.x;
    const float* src; unsigned short* dst; int j;
    if (i < 2097152)      { src = x;   dst = xb;    j = i; }
    else if (i < 3145728) { src = wq;  dst = wqkvb; j = i - 2097152; }
    else if (i < 3670016) { src = wkv; dst = wqkvb + (size_t)2048 * 2048; j = i - 3145728; }
    else                  { src = wo;  dst = wob;   j = i - 3670016; }
    float4 f = ((const float4*)src)[j];
    ushort4 u;
    u.x = f2bf(f.x); u.y = f2bf(f.y); u.z = f2bf(f.z); u.w = f2bf(f.w);
    ((ushort4*)dst)[j] = u;
}

// ---------- GEMM 8-phase: C[M,N] = A[M,K] @ B[N,K]^T ----------
// BM=256, BN=NREP*64, BK=64, 512 threads = 8 waves (2 wm x 4 wn).
// m201-style phase: {ds_read frags; stage pair; [counted vmcnt]; s_barrier;
//                    lgkmcnt(0)+sched_barrier; setprio(1); MFMA; setprio(0); s_barrier}
// XCD-aware block swizzle (T1): default linearization spreads B-panel-sharing
// blocks across all 8 XCD L2s (measured 57.4MB fetch vs 29.4MB unique = 2x).
// Remap each XCD to a contiguous 4x8 tile rect (bijective on the 16x16 grid).
// If VtOut != nullptr (QKV gemm): cols >= 2560 are V -> written TRANSPOSED to
// VtOut[(b*4+kvh)*128+d][t] only (QKVb V-region is never read downstream).
template <int NREP, typename OutT>
__global__ __launch_bounds__(512, 2) void gemm8p(const unsigned short* __restrict__ A,
                                                 const unsigned short* __restrict__ B,
                                                 OutT* __restrict__ C,
                                                 unsigned short* __restrict__ VtOut,
                                                 int N, int K, int NT,
                                                 int ncut, float qscale) {
    constexpr int NCH = 4 + NREP;   // chunks per K-tile
    __shared__ __attribute__((aligned(16))) unsigned short LA[2][256 * 64];
    __shared__ __attribute__((aligned(16))) unsigned short LB[2][NREP * 64 * 64];

    const int tid  = threadIdx.x;
    const int lane = tid & 63;
    const int w    = tid >> 6;          // 0..7
    const int quad = lane >> 4;
    const int l16  = lane & 15;
    const int wm   = w >> 2;            // 0..1
    const int wn   = w & 3;             // 0..3

    // XCD swizzle: lid%8 = XCD (round-robin dispatch); give each XCD a 4x8 rect.
    const int lid = blockIdx.x + (int)gridDim.x * blockIdx.y;
    const int xcd = lid & 7, idx = lid >> 3;
    const int bx  = (xcd & 3) * 4 + (idx & 3);
    const int by  = (xcd >> 2) * 8 + (idx >> 2);
    const int m0  = bx * 256;
    const int n0  = by * (NREP * 64);
    const int swz = (l16 & 7) << 3;     // read-side XOR swizzle (elements)

    // staging: lane -> (row-in-8, slot); source slot inverse-swizzled
    const int lr = lane >> 3;
    const int ls = lane & 7;
    const int ss = ls ^ lr;
    const unsigned short* aSrc = A + (size_t)(m0 + w * 8 + lr) * K + ss * 8;
    const unsigned short* bSrc = B + (size_t)(n0 + w * 8 + lr) * K + ss * 8;

    f32x4 acc[8][NREP] = {};

    // stage one 8KB chunk (slot si of K-tile t) into buffer nb
    auto stage1 = [&](int nb, int t, int si) {
        if (si >= NCH) return;
        if (si < NREP) {
            async16(bSrc + (size_t)si * 64 * K + t * 64, &LB[nb][(si * 64 + w * 8) * 64]);
        } else {
            int j = si - NREP;
            int c = (j == 0) ? 0 : (j == 1) ? 2 : (j == 2) ? 1 : 3;   // A chunk order c0,c2,c1,c3
            async16(aSrc + (size_t)c * 64 * K + t * 64, &LA[nb][(c * 64 + w * 8) * 64]);
        }
    };

    // one phase (q = m-pair index, compile-time at every call site)
    auto phase = [&](int cur, int q, bf16x8 (&bf)[NREP][2], int tn, bool last) {
        bf16x8 af[2][2];
        if (q == 0) {
#pragma unroll
            for (int n = 0; n < NREP; ++n)
#pragma unroll
                for (int kk = 0; kk < 2; ++kk)
                    bf[n][kk] = *(const bf16x8*)&LB[cur][(size_t)(wn * (NREP * 16) + n * 16 + l16) * 64
                                                         + ((kk * 32 + quad * 8) ^ swz)];
        }
#pragma unroll
        for (int mi = 0; mi < 2; ++mi)
#pragma unroll
            for (int kk = 0; kk < 2; ++kk)
                af[mi][kk] = *(const bf16x8*)&LA[cur][(size_t)(wm * 128 + (q * 2 + mi) * 16 + l16) * 64
                                                      + ((kk * 32 + quad * 8) ^ swz)];
        if (!last) { stage1(cur ^ 1, tn, 2 * q); stage1(cur ^ 1, tn, 2 * q + 1); }
        if (q == 1) {
            if (last) asm volatile("s_waitcnt vmcnt(0)" ::: "memory");
            else      asm volatile("s_waitcnt vmcnt(4)" ::: "memory");
        }
        if (q == 3 && !last) asm volatile("s_waitcnt vmcnt(2)" ::: "memory");
        __builtin_amdgcn_s_barrier();
        asm volatile("s_waitcnt lgkmcnt(0)" ::: "memory");
        __builtin_amdgcn_sched_barrier(0);
        __builtin_amdgcn_s_setprio(1);
#pragma unroll
        for (int mi = 0; mi < 2; ++mi)
#pragma unroll
            for (int n = 0; n < NREP; ++n)
#pragma unroll
                for (int kk = 0; kk < 2; ++kk)
                    acc[q * 2 + mi][n] = __builtin_amdgcn_mfma_f32_16x16x32_bf16(
                        af[mi][kk], bf[n][kk], acc[q * 2 + mi][n], 0, 0, 0);
        __builtin_amdgcn_s_setprio(0);
        __builtin_amdgcn_s_barrier();
    };

    auto ktile = [&](int cur, int tn, bool last) {
        bf16x8 bf[NREP][2];
        phase(cur, 0, bf, tn, last);
        phase(cur, 1, bf, tn, last);
        phase(cur, 2, bf, tn, last);
        phase(cur, 3, bf, tn, last);
    };

    // prologue: stage all chunks of tile 0 into buffer 0; entry guarantee
#pragma unroll
    for (int s = 0; s < NCH; ++s) stage1(0, 0, s);
    asm volatile("s_waitcnt vmcnt(2)" ::: "memory");
    __builtin_amdgcn_s_barrier();

    int cur = 0;
    for (int t = 0; t < NT - 1; ++t) {
        ktile(cur, t + 1, false);
        cur ^= 1;
    }
    ktile(cur, 0, true);

    // epilogue
#pragma unroll
    for (int m = 0; m < 8; ++m) {
        int row = m0 + wm * 128 + m * 16 + quad * 4;
#pragma unroll
        for (int n = 0; n < NREP; ++n) {
            int col = n0 + wn * (NREP * 16) + n * 16 + l16;
            f32x4 v = acc[m][n];
            float s = (col < ncut) ? qscale : 1.0f;
            if (VtOut != nullptr && col >= 2560) {
                // V column -> transposed write only: Vt[b*512 + (col-2560)][t0..t0+3]
                int bb = row >> 11, t0 = row & 2047;
                ushort4 o;
                o.x = f2bf(v[0]); o.y = f2bf(v[1]); o.z = f2bf(v[2]); o.w = f2bf(v[3]);
                *(ushort4*)(VtOut + ((size_t)(bb * 512 + (col - 2560))) * 2048 + t0) = o;
            } else {
#pragma unroll
                for (int j = 0; j < 4; ++j) {
                    float vj = v[j] * s;
                    if constexpr (sizeof(OutT) == 4)
                        C[(size_t)(row + j) * N + col] = vj;
                    else
                        C[(size_t)(row + j) * N + col] = f2bf(vj);
                }
            }
        }
    }
}

// ---------- Flash attention v9b: split-K + permlane P-redistribution ----------
__global__ __launch_bounds__(256, 2) void attn_fwd9(const unsigned short* __restrict__ QKV,
                                                    const unsigned short* __restrict__ Vt,
                                                    unsigned short* __restrict__ Opart,
                                                    float* __restrict__ lpart) {
    __shared__ __attribute__((aligned(16))) unsigned short Ks[64 * 128];     // single
    __shared__ __attribute__((aligned(16))) unsigned short Vs[2][128 * 64];  // double

    const int tid  = threadIdx.x;
    const int lane = tid & 63;
    const int w    = tid >> 6;
    const int quad = lane >> 4;
    const int l16  = lane & 15;
    const int swz  = (l16 & 7) << 3;

    const int hb   = blockIdx.x;
    const int h    = hb & 15;
    const int b    = hb >> 4;
    const int y    = blockIdx.y;
    const int p    = 15 - (y >> 1);
    const int half = y & 1;
    const int kvh  = h >> 2;
    const float M_FIX = 12.0f;

    const int ntot   = p + 1;
    const int tstart = half ? ntot : 0;
    const int tend   = half ? 2 * ntot : ntot;

    const int qbase = p * 128;
    const int qw0   = qbase + w * 32;
    const int qw1   = qw0 + 16;

    bf16x8 qf[2][4];
#pragma unroll
    for (int g = 0; g < 2; ++g)
#pragma unroll
        for (int kd = 0; kd < 4; ++kd)
            qf[g][kd] = *(const bf16x8*)(QKV + (size_t)(b * 2048 + qw0 + g * 16 + l16) * 3072
                                         + h * 128 + kd * 32 + quad * 8);

    f32x4 oacc[2][8] = {};
    f32x4 rs4[2] = {};

    const unsigned short* gk[4];
    const unsigned short* gv[4];
#pragma unroll
    for (int pp = 0; pp < 4; ++pp) {
        int r  = (4 * w + pp) * 4 + (lane >> 4);
        int s  = lane & 15;
        int sp = (s & 8) | ((s ^ r) & 7);
        gk[pp] = QKV + (size_t)(b * 2048 + r) * 3072 + 2048 + kvh * 128 + sp * 8;
        int d  = (4 * w + pp) * 8 + (lane >> 3);
        int sv = (lane & 7) ^ (d & 7);
        gv[pp] = Vt + ((size_t)(b * 4 + kvh) * 128 + d) * 2048 + sv * 8;
    }

    auto stageK = [&](int t) {
        const size_t ko = (size_t)t * 64;
#pragma unroll
        for (int pp = 0; pp < 4; ++pp)
            async16(gk[pp] + ko * 3072, &Ks[(4 * w + pp) * 512]);
    };
    auto stageV = [&](int nb, int t) {
        const size_t ko = (size_t)t * 64;
#pragma unroll
        for (int pp = 0; pp < 4; ++pp)
            async16(gv[pp] + ko, &Vs[nb][(4 * w + pp) * 512]);
    };

    stageK(tstart);
    stageV(0, tstart);
    int cur = 0;

    for (int t = tstart; t < tend; ++t) {
        __syncthreads();                          // sync1: K(t)/V(t) DMA drained
        if (t + 1 < tend) stageV(cur ^ 1, t + 1); // early V prefetch (Vs[nxt] free)
        const int k0 = t * 64;
        const bool liveW = (k0 <= qw0 + 15);
        const bool live1 = (k0 <= qw1 + 15);

        bf16x8 pa[2][2];
        if (liveW) {
            // ---- S^T = K Q^T : lane holds q-row = l16, keys kt*16+quad*4+j ----
            f32x4 sacc[2][4] = {};
            __builtin_amdgcn_s_setprio(1);
#pragma unroll
            for (int kt = 0; kt < 4; ++kt) {
                bf16x8 kf[4];
#pragma unroll
                for (int kd = 0; kd < 4; ++kd)
                    kf[kd] = *(const bf16x8*)&Ks[(kt * 16 + l16) * 128
                                                 + ((kd * 32 + quad * 8) ^ swz)];
#pragma unroll
                for (int kd = 0; kd < 4; ++kd)
                    sacc[0][kt] = __builtin_amdgcn_mfma_f32_16x16x32_bf16(kf[kd], qf[0][kd], sacc[0][kt], 0, 0, 0);
                if (live1) {
#pragma unroll
                    for (int kd = 0; kd < 4; ++kd)
                        sacc[1][kt] = __builtin_amdgcn_mfma_f32_16x16x32_bf16(kf[kd], qf[1][kd], sacc[1][kt], 0, 0, 0);
                }
            }
            __builtin_amdgcn_s_setprio(0);

            // ---- in-register softmax + pack + permlane redistribution ----
#pragma unroll
            for (int g = 0; g < 2; ++g) {
                if (g == 1 && !live1) continue;
                const int qwg  = qw0 + g * 16;
                const bool diag = (k0 + 63 > qwg);
                const int qrow = qwg + l16;
                unsigned int pk[4][2];
#pragma unroll
                for (int kt = 0; kt < 4; ++kt) {
                    float pvv[4];
#pragma unroll
                    for (int j = 0; j < 4; ++j) {
                        float pv = __expf(sacc[g][kt][j] - M_FIX);
                        if (diag) {
                            int key = k0 + kt * 16 + quad * 4 + j;
                            if (key > qrow) pv = 0.f;
                        }
                        rs4[g][j] += pv;
                        pvv[j] = pv;
                    }
                    asm("v_cvt_pk_bf16_f32 %0, %1, %2" : "=v"(pk[kt][0]) : "v"(pvv[0]), "v"(pvv[1]));
                    asm("v_cvt_pk_bf16_f32 %0, %1, %2" : "=v"(pk[kt][1]) : "v"(pvv[2]), "v"(pvv[3]));
                }
#pragma unroll
                for (int ks = 0; ks < 2; ++ks) {
                    unsigned int d0 = pk[2 * ks][0], s0 = pk[2 * ks + 1][0];
                    unsigned int d1 = pk[2 * ks][1], s1 = pk[2 * ks + 1][1];
                    asm("v_permlane32_swap_b32 %0, %1" : "+v"(d0), "+v"(s0));
                    asm("v_permlane16_swap_b32 %0, %1" : "+v"(d0), "+v"(s0));
                    asm("v_permlane32_swap_b32 %0, %1" : "+v"(d1), "+v"(s1));
                    asm("v_permlane16_swap_b32 %0, %1" : "+v"(d1), "+v"(s1));
                    u32x4 tt;
                    tt.x = d0;
                    tt.y = d1;
                    tt.z = s0;
                    tt.w = s1;
                    pa[g][ks] = __builtin_bit_cast(bf16x8, tt);
                }
            }
        }

        // sync2: all Ks ds_reads retired (lgkm-only; V prefetch stays in flight)
        asm volatile("s_waitcnt lgkmcnt(0)" ::: "memory");
        __builtin_amdgcn_s_barrier();
        if (t + 1 < tend) stageK(t + 1);          // overwrite single Ks with K(t+1)

        if (liveW) {
            // ---- O += P V ----
            __builtin_amdgcn_s_setprio(1);
#pragma unroll
            for (int dt = 0; dt < 8; ++dt) {
                bf16x8 vf[2];
#pragma unroll
                for (int ks = 0; ks < 2; ++ks)
                    vf[ks] = *(const bf16x8*)&Vs[cur][(dt * 16 + l16) * 64
                                                      + ((ks * 32 + quad * 8) ^ swz)];
#pragma unroll
                for (int ks = 0; ks < 2; ++ks)
                    oacc[0][dt] = __builtin_amdgcn_mfma_f32_16x16x32_bf16(pa[0][ks], vf[ks], oacc[0][dt], 0, 0, 0);
                if (live1) {
#pragma unroll
                    for (int ks = 0; ks < 2; ++ks)
                        oacc[1][dt] = __builtin_amdgcn_mfma_f32_16x16x32_bf16(pa[1][ks], vf[ks], oacc[1][dt], 0, 0, 0);
                }
            }
            __builtin_amdgcn_s_setprio(0);
        }
        cur ^= 1;
    }

    // ---- epilogue: UNNORMALIZED partial O (bf16) and partial l (fp32) ----
#pragma unroll
    for (int g = 0; g < 2; ++g) {
        float r = (rs4[g][0] + rs4[g][1]) + (rs4[g][2] + rs4[g][3]);
        r += __shfl_xor(r, 16, 64);
        r += __shfl_xor(r, 32, 64);
        if (lane < 16)
            lpart[((size_t)(half * 2 + b) * 16 + h) * 2048 + qw0 + g * 16 + lane] = r;
#pragma unroll
        for (int dt = 0; dt < 8; ++dt)
#pragma unroll
            for (int j = 0; j < 4; ++j) {
                int qrow = qw0 + g * 16 + quad * 4 + j;
                Opart[(size_t)(half * 4096 + b * 2048 + qrow) * 2048 + h * 128 + dt * 16 + l16] =
                    f2bf(oacc[g][dt][j]);
            }
    }
}

// ---------- combine: O = (O_A + O_B) / (l_A + l_B) ----------
__global__ __launch_bounds__(256) void combine(const unsigned short* __restrict__ Opart,
                                               const float* __restrict__ lpart,
                                               unsigned short* __restrict__ O) {
    const int r   = blockIdx.x;
    const int b   = r >> 11, row = r & 2047;
    const int col = threadIdx.x * 8;
    const int h   = col >> 7;
    bf16x8 a = *(const bf16x8*)(Opart + (size_t)r * 2048 + col);
    bf16x8 c = *(const bf16x8*)(Opart + (size_t)(4096 + r) * 2048 + col);
    float la = lpart[((size_t)(0 * 2 + b) * 16 + h) * 2048 + row];
    float lb = lpart[((size_t)(1 * 2 + b) * 16 + h) * 2048 + row];
    float inv = 1.0f / (la + lb);
    bf16x8 o;
#pragma unroll
    for (int i = 0; i < 8; ++i)
        o[i] = (short)f2bf((bf2f(a[i]) + bf2f(c[i])) * inv);
    *(bf16x8*)(O + (size_t)r * 2048 + col) = o;
}

// ---------- launch ----------
extern "C" void kernel_launch(void* const* d_in, const int* in_sizes, int n_in,
                              void* d_out, int out_size, void* d_ws, size_t ws_size,
                              hipStream_t stream) {
    const float* x   = (const float*)d_in[0];   // [2,2048,2048]
    const float* wq  = (const float*)d_in[1];   // [2048,2048]
    const float* wkv = (const float*)d_in[2];   // [1024,2048]
    const float* wo  = (const float*)d_in[3];   // [2048,2048]
    float* out = (float*)d_out;                 // [2,2048,2048] fp32

    char* ws = (char*)d_ws;
    size_t off = 0;
    auto alloc = [&](size_t bytes) { size_t o = off; off += (bytes + 255) & ~(size_t)255; return o; };
    unsigned short* xb    = (unsigned short*)(ws + alloc((size_t)4096 * 2048 * 2));
    unsigned short* wqkvb = (unsigned short*)(ws + alloc((size_t)3072 * 2048 * 2));
    unsigned short* wob   = (unsigned short*)(ws + alloc((size_t)2048 * 2048 * 2));
    unsigned short* QKVb  = (unsigned short*)(ws + alloc((size_t)4096 * 3072 * 2));
    unsigned short* Ab    = (unsigned short*)(ws + alloc((size_t)4096 * 2048 * 2));
    unsigned short* Vtb   = (unsigned short*)(ws + alloc((size_t)2 * 4 * 128 * 2048 * 2));
    unsigned short* Opart = (unsigned short*)(ws + alloc((size_t)2 * 4096 * 2048 * 2));
    float*          lpart = (float*)(ws + alloc((size_t)2 * 2 * 16 * 2048 * 4));

    const float qscale = 0.08838834764831845f;  // 1/sqrt(128), folded into Q

    // fused casts (x, wq, wkv, wo) in one launch
    castall<<<18432, 256, 0, stream>>>(x, wq, wkv, wo, xb, wqkvb, wob);

    // fused QKV projection (Q cols pre-scaled; V cols written transposed to Vtb)
    gemm8p<3, unsigned short><<<dim3(16, 16), 512, 0, stream>>>(xb, wqkvb, QKVb, Vtb,
                                                                3072, 2048, 32, 2048, qscale);

    // attention: 128-row q-jobs, split-K halves, heavy-first LPT refill; then combine
    attn_fwd9<<<dim3(32, 32), 256, 0, stream>>>(QKVb, Vtb, Opart, lpart);
    combine<<<4096, 256, 0, stream>>>(Opart, lpart, Ab);

    // output projection (fp32 out): 256x128 tiles -> 256 blocks (full GPU)
    gemm8p<2, float><<<dim3(16, 16), 512, 0, stream>>>(Ab, wob, out, nullptr,
                                                       2048, 2048, 32, 0, 1.0f);
}